// Round 1
// baseline (947.701 us; speedup 1.0000x reference)
//
#include <hip/hip_runtime.h>
#include <cstdint>
#include <cstddef>

#define NN 50000
#define NE 800000
#define NEG_FLT_MAX (-3.402823466e38f)

__device__ __forceinline__ float lrelu_f(float x){ return x >= 0.f ? x : 0.2f*x; }
__device__ __forceinline__ float elu_f(float x){ return x > 0.f ? x : __expf(x) - 1.f; }

// ---------------- counting sort (per edge type, by dst) ----------------
__global__ void hist_kernel(const int* __restrict__ e0, const int* __restrict__ e1,
                            int* __restrict__ c0, int* __restrict__ c1){
  int i = blockIdx.x*256 + threadIdx.x;
  const int* e = blockIdx.y ? e1 : e0;
  int* c = blockIdx.y ? c1 : c0;
  if (i < NE) atomicAdd(&c[e[NE + i]], 1);
}

__global__ __launch_bounds__(1024) void scan_kernel(int* d0, int* cu0, int* d1, int* cu1){
  int* data = blockIdx.x ? d1 : d0;
  int* cur  = blockIdx.x ? cu1 : cu0;
  __shared__ int sh[1024];
  const int t = threadIdx.x;
  int carry = 0;
  for (int base = 0; base < NN; base += 1024){
    int i = base + t;
    int v = (i < NN) ? data[i] : 0;
    sh[t] = v; __syncthreads();
    for (int off = 1; off < 1024; off <<= 1){
      int x = (t >= off) ? sh[t-off] : 0;
      __syncthreads();
      sh[t] += x;
      __syncthreads();
    }
    int incl = sh[t];
    int tot  = sh[1023];
    __syncthreads();
    int excl = carry + incl - v;
    if (i < NN){ data[i] = excl; cur[i] = excl; }
    carry += tot;
  }
  if (t == 0) data[NN] = carry;
}

__global__ void scatter_kernel(const int* __restrict__ e0, const int* __restrict__ e1,
                               int* __restrict__ cu0, int* __restrict__ cu1,
                               int* __restrict__ s0, int* __restrict__ s1){
  int i = blockIdx.x*256 + threadIdx.x;
  const int* e = blockIdx.y ? e1 : e0;
  int* cu = blockIdx.y ? cu1 : cu0;
  int* ss = blockIdx.y ? s1 : s0;
  if (i < NE){
    int d = e[NE + i];
    int p = atomicAdd(&cu[d], 1);
    ss[p] = e[i];
  }
}

// ---------------- tiled fp32 GEMM: C = act(A[M,K] @ W[K,N] (+bias)) ----------------
// TILE_M=64, TILE_K=64, TILE_N=TN (64 or 32). 256 threads; thread computes TN/16 rows x 4 cols.
template<int TN, bool ELU>
__global__ __launch_bounds__(256) void gemm_kernel(
    const float* __restrict__ A, const float* __restrict__ W,
    const float* __restrict__ bias, float* __restrict__ C,
    int M, int K, int N)
{
  constexpr int CG  = TN/4;    // column groups (float4 each)
  constexpr int RPT = TN/16;   // rows per thread
  __shared__ float As[64][68]; // +4 pad: keeps float4 writes aligned, rows on distinct banks
  __shared__ float Ws[64][TN];
  const int t  = threadIdx.x;
  const int tx = t % CG;
  const int ty = t / CG;
  const int m0 = blockIdx.x * 64;
  const int n0 = blockIdx.y * TN;
  float acc[RPT][4];
  #pragma unroll
  for (int i=0;i<RPT;i++){ acc[i][0]=0.f; acc[i][1]=0.f; acc[i][2]=0.f; acc[i][3]=0.f; }

  for (int kt = 0; kt < K; kt += 64){
    #pragma unroll
    for (int i=0;i<4;i++){
      int li = t + i*256;
      int r = li >> 4, cv = li & 15;
      float4 v = make_float4(0.f,0.f,0.f,0.f);
      int m = m0 + r;
      if (m < M) v = *(const float4*)(A + (size_t)m*K + kt + cv*4);
      *(float4*)&As[r][cv*4] = v;
    }
    #pragma unroll
    for (int i=0;i<TN/16;i++){
      int li = t + i*256;
      int r = li / CG, cv = li % CG;
      *(float4*)&Ws[r][cv*4] = *(const float4*)(W + (size_t)(kt + r)*N + n0 + cv*4);
    }
    __syncthreads();
    #pragma unroll 16
    for (int k=0;k<64;k++){
      float4 wv = *(const float4*)&Ws[k][tx*4];
      #pragma unroll
      for (int i=0;i<RPT;i++){
        float a = As[ty*RPT + i][k];
        acc[i][0] += a*wv.x; acc[i][1] += a*wv.y;
        acc[i][2] += a*wv.z; acc[i][3] += a*wv.w;
      }
    }
    __syncthreads();
  }
  #pragma unroll
  for (int i=0;i<RPT;i++){
    int m = m0 + ty*RPT + i;
    if (m < M){
      float4 o = make_float4(acc[i][0],acc[i][1],acc[i][2],acc[i][3]);
      if (bias){
        float4 b = *(const float4*)(bias + n0 + tx*4);
        o.x+=b.x; o.y+=b.y; o.z+=b.z; o.w+=b.w;
      }
      if (ELU){ o.x=elu_f(o.x); o.y=elu_f(o.y); o.z=elu_f(o.z); o.w=elu_f(o.w); }
      *(float4*)(C + (size_t)m*N + n0 + tx*4) = o;
    }
  }
}

// ---------------- collapse attention vectors: cw[h,k] = sum_c W[k,h*C+c]*a[h,c] ----------------
struct CollapseJob { const float* W; const float* a; float* out; int K,H,C; };
struct CollapseArgs { CollapseJob j[8]; };
__global__ void collapse_kernel(CollapseArgs args){
  CollapseJob jb = args.j[blockIdx.x];
  int t = threadIdx.x;
  if (t < jb.K * jb.H){
    int k = t / jb.H, h = t % jb.H;
    const float* wr = jb.W + (size_t)k * (jb.H*jb.C) + h*jb.C;
    const float* ar = jb.a + h*jb.C;
    float s = 0.f;
    for (int c=0;c<jb.C;c++) s += wr[c]*ar[c];
    jb.out[h*jb.K + k] = s;   // layout [H,K] for conflict-free LDS reads in matvec
  }
}

// ---------------- al[n,h] = X[n,:] . cw[h,:]  (wave per node) ----------------
struct MvJob { const float* X; const float* cw; float* out; };
template<int K, int H>
__global__ __launch_bounds__(256) void matvec_kernel(MvJob j0, MvJob j1, MvJob j2, MvJob j3){
  MvJob jb = (blockIdx.y==0)?j0:(blockIdx.y==1)?j1:(blockIdx.y==2)?j2:j3;
  __shared__ float cw[K*H];
  for (int i=threadIdx.x; i<K*H; i+=256) cw[i] = jb.cw[i];
  __syncthreads();
  const int wid = threadIdx.x>>6, lane = threadIdx.x&63;
  const int node = blockIdx.x*4 + wid;
  if (node >= NN) return;
  float p[H];
  #pragma unroll
  for (int h=0;h<H;h++) p[h]=0.f;
  #pragma unroll
  for (int kk=0; kk<K/64; kk++){
    float x = jb.X[(size_t)node*K + kk*64 + lane];
    #pragma unroll
    for (int h=0;h<H;h++) p[h] += x*cw[h*K + kk*64 + lane];
  }
  #pragma unroll
  for (int off=32; off>0; off>>=1){
    #pragma unroll
    for (int h=0;h<H;h++) p[h] += __shfl_xor(p[h], off, 64);
  }
  if (lane==0){
    #pragma unroll
    for (int h=0;h<H;h++) jb.out[(size_t)node*H + h] = p[h];
  }
}

// ---------------- GAT aggregation ----------------
struct AggJob {
  const int* offs; const int* ssrc;
  const float* hs; const float* als; const float* ald;
  const float* bias; float* out;
};

// layer 0: H=4, C=64 (256 ch). One wave per dst; lane l owns channels 4l..4l+3 (head l>>4).
__global__ __launch_bounds__(256) void agg0_kernel(AggJob ja, AggJob jbb){
  const AggJob jb = blockIdx.y ? jbb : ja;
  const int wid = threadIdx.x>>6, lane = threadIdx.x&63;
  const int dst = blockIdx.x*4 + wid;
  if (dst >= NN) return;
  const int b0 = jb.offs[dst], b1 = jb.offs[dst+1];
  const float4 ad = *(const float4*)(jb.ald + (size_t)dst*4);
  float mx0=NEG_FLT_MAX, mx1=NEG_FLT_MAX, mx2=NEG_FLT_MAX, mx3=NEG_FLT_MAX;
  for (int e=b0+lane; e<b1; e+=64){
    int s = jb.ssrc[e];
    float4 as = *(const float4*)(jb.als + (size_t)s*4);
    mx0 = fmaxf(mx0, lrelu_f(as.x+ad.x));
    mx1 = fmaxf(mx1, lrelu_f(as.y+ad.y));
    mx2 = fmaxf(mx2, lrelu_f(as.z+ad.z));
    mx3 = fmaxf(mx3, lrelu_f(as.w+ad.w));
  }
  #pragma unroll
  for (int off=32; off>0; off>>=1){
    mx0 = fmaxf(mx0, __shfl_xor(mx0, off, 64));
    mx1 = fmaxf(mx1, __shfl_xor(mx1, off, 64));
    mx2 = fmaxf(mx2, __shfl_xor(mx2, off, 64));
    mx3 = fmaxf(mx3, __shfl_xor(mx3, off, 64));
  }
  const int h = lane >> 4;
  const float mh  = (h<2) ? (h==0?mx0:mx1) : (h==2?mx2:mx3);
  const float adh = (h<2) ? (h==0?ad.x:ad.y) : (h==2?ad.z:ad.w);
  float4 acc = make_float4(0.f,0.f,0.f,0.f);
  float den = 0.f;
  for (int e=b0; e<b1; ++e){
    int s = jb.ssrc[e];
    float a = lrelu_f(jb.als[(size_t)s*4 + h] + adh);
    float w = __expf(a - mh);
    float4 v = *(const float4*)(jb.hs + (size_t)s*256 + lane*4);
    acc.x += w*v.x; acc.y += w*v.y; acc.z += w*v.z; acc.w += w*v.w;
    den += w;
  }
  const float inv = 1.f/(den + 1e-16f);
  float4 b = *(const float4*)(jb.bias + lane*4);
  float4 o;
  o.x = elu_f(acc.x*inv + b.x);
  o.y = elu_f(acc.y*inv + b.y);
  o.z = elu_f(acc.z*inv + b.z);
  o.w = elu_f(acc.w*inv + b.w);
  *(float4*)(jb.out + (size_t)dst*256 + lane*4) = o;
}

// layer 1: H=1, C=32. One wave per dst; 8 edge slots x (8 lanes * float4) per edge row.
__global__ __launch_bounds__(256) void agg1_kernel(AggJob ja, AggJob jbb){
  const AggJob jb = blockIdx.y ? jbb : ja;
  const int wid = threadIdx.x>>6, lane = threadIdx.x&63;
  const int dst = blockIdx.x*4 + wid;
  if (dst >= NN) return;
  const int b0 = jb.offs[dst], b1 = jb.offs[dst+1];
  const float ad = jb.ald[dst];
  float mx = NEG_FLT_MAX;
  for (int e=b0+lane; e<b1; e+=64)
    mx = fmaxf(mx, lrelu_f(jb.als[jb.ssrc[e]] + ad));
  #pragma unroll
  for (int off=32; off>0; off>>=1) mx = fmaxf(mx, __shfl_xor(mx, off, 64));
  const int slot = lane>>3, c4 = (lane&7)*4;
  float4 acc = make_float4(0.f,0.f,0.f,0.f);
  float den = 0.f;
  for (int e=b0+slot; e<b1; e+=8){
    int s = jb.ssrc[e];
    float w = __expf(lrelu_f(jb.als[s] + ad) - mx);
    float4 v = *(const float4*)(jb.hs + (size_t)s*32 + c4);
    acc.x += w*v.x; acc.y += w*v.y; acc.z += w*v.z; acc.w += w*v.w;
    den += w;
  }
  #pragma unroll
  for (int off=32; off>=8; off>>=1){
    acc.x += __shfl_xor(acc.x, off, 64);
    acc.y += __shfl_xor(acc.y, off, 64);
    acc.z += __shfl_xor(acc.z, off, 64);
    acc.w += __shfl_xor(acc.w, off, 64);
    den   += __shfl_xor(den,   off, 64);
  }
  if (lane < 8){
    const float inv = 1.f/(den + 1e-16f);
    float4 b = *(const float4*)(jb.bias + c4);
    float4 o = make_float4(acc.x*inv+b.x, acc.y*inv+b.y, acc.z*inv+b.z, acc.w*inv+b.w);
    *(float4*)(jb.out + (size_t)dst*32 + c4) = o;
  }
}

// ---------------- host glue ----------------
extern "C" void kernel_launch(void* const* d_in, const int* in_sizes, int n_in,
                              void* d_out, int out_size, void* d_ws, size_t ws_size,
                              hipStream_t stream)
{
  (void)in_sizes; (void)n_in; (void)out_size; (void)ws_size;
  const float* x_user   = (const float*)d_in[0];
  const float* x_item   = (const float*)d_in[1];
  const int*   e_u2i    = (const int*)  d_in[2];
  const int*   e_i2u    = (const int*)  d_in[3];
  const float* p_user_w = (const float*)d_in[4];
  const float* p_user_b = (const float*)d_in[5];
  const float* p_item_w = (const float*)d_in[6];
  const float* p_item_b = (const float*)d_in[7];
  const float* l0_u2i_ws=(const float*)d_in[8];
  const float* l0_u2i_wd=(const float*)d_in[9];
  const float* l0_u2i_as=(const float*)d_in[10];
  const float* l0_u2i_ad=(const float*)d_in[11];
  const float* l0_u2i_b =(const float*)d_in[12];
  const float* l0_i2u_ws=(const float*)d_in[13];
  const float* l0_i2u_wd=(const float*)d_in[14];
  const float* l0_i2u_as=(const float*)d_in[15];
  const float* l0_i2u_ad=(const float*)d_in[16];
  const float* l0_i2u_b =(const float*)d_in[17];
  const float* l1_u2i_ws=(const float*)d_in[18];
  const float* l1_u2i_wd=(const float*)d_in[19];
  const float* l1_u2i_as=(const float*)d_in[20];
  const float* l1_u2i_ad=(const float*)d_in[21];
  const float* l1_u2i_b =(const float*)d_in[22];
  const float* l1_i2u_ws=(const float*)d_in[23];
  const float* l1_i2u_wd=(const float*)d_in[24];
  const float* l1_i2u_as=(const float*)d_in[25];
  const float* l1_i2u_ad=(const float*)d_in[26];
  const float* l1_i2u_b =(const float*)d_in[27];

  char* base = (char*)d_ws;
  size_t off = 0;
  auto alloc = [&](size_t bytes)->void*{
    void* p = base + off;
    off += (bytes + 255) & ~(size_t)255;
    return p;
  };
  int* offs_u2i = (int*)alloc((size_t)2*(NN+1)*sizeof(int)); // both offs contiguous -> one memset
  int* offs_i2u = offs_u2i + (NN+1);
  int* cur_u2i  = (int*)alloc((size_t)NN*sizeof(int));
  int* cur_i2u  = (int*)alloc((size_t)NN*sizeof(int));
  int* ssrc_u2i = (int*)alloc((size_t)NE*sizeof(int));
  int* ssrc_i2u = (int*)alloc((size_t)NE*sizeof(int));
  float* hu       = (float*)alloc((size_t)NN*64*sizeof(float));
  float* hi       = (float*)alloc((size_t)NN*64*sizeof(float));
  float* hs0_u2i  = (float*)alloc((size_t)NN*256*sizeof(float));
  float* hs0_i2u  = (float*)alloc((size_t)NN*256*sizeof(float));
  float* hu1      = (float*)alloc((size_t)NN*256*sizeof(float));
  float* hi1      = (float*)alloc((size_t)NN*256*sizeof(float));
  float* hs1_u2i  = (float*)alloc((size_t)NN*32*sizeof(float));
  float* hs1_i2u  = (float*)alloc((size_t)NN*32*sizeof(float));
  float* als0_u2i = (float*)alloc((size_t)NN*4*sizeof(float));
  float* ald0_u2i = (float*)alloc((size_t)NN*4*sizeof(float));
  float* als0_i2u = (float*)alloc((size_t)NN*4*sizeof(float));
  float* ald0_i2u = (float*)alloc((size_t)NN*4*sizeof(float));
  float* als1_u2i = (float*)alloc((size_t)NN*sizeof(float));
  float* ald1_u2i = (float*)alloc((size_t)NN*sizeof(float));
  float* als1_i2u = (float*)alloc((size_t)NN*sizeof(float));
  float* ald1_i2u = (float*)alloc((size_t)NN*sizeof(float));
  float* cw0s_u2i = (float*)alloc(256*sizeof(float));
  float* cw0d_u2i = (float*)alloc(256*sizeof(float));
  float* cw0s_i2u = (float*)alloc(256*sizeof(float));
  float* cw0d_i2u = (float*)alloc(256*sizeof(float));
  float* cw1s_u2i = (float*)alloc(256*sizeof(float));
  float* cw1d_u2i = (float*)alloc(256*sizeof(float));
  float* cw1s_i2u = (float*)alloc(256*sizeof(float));
  float* cw1d_i2u = (float*)alloc(256*sizeof(float));

  const int GEB = (NE + 255)/256;
  const int GM  = (NN + 63)/64;

  // ---- counting sort of both edge lists by dst ----
  hipMemsetAsync(offs_u2i, 0, (size_t)2*(NN+1)*sizeof(int), stream);
  hist_kernel   <<<dim3(GEB,2), 256, 0, stream>>>(e_u2i, e_i2u, offs_u2i, offs_i2u);
  scan_kernel   <<<2, 1024, 0, stream>>>(offs_u2i, cur_u2i, offs_i2u, cur_i2u);
  scatter_kernel<<<dim3(GEB,2), 256, 0, stream>>>(e_u2i, e_i2u, cur_u2i, cur_i2u, ssrc_u2i, ssrc_i2u);

  // ---- input projections (+bias +ELU) ----
  gemm_kernel<64,true><<<dim3(GM,1), 256, 0, stream>>>(x_user, p_user_w, p_user_b, hu, NN, 128, 64);
  gemm_kernel<64,true><<<dim3(GM,1), 256, 0, stream>>>(x_item, p_item_w, p_item_b, hi, NN, 128, 64);

  // ---- collapse attention vectors through the linear weights ----
  CollapseArgs ca;
  ca.j[0] = {l0_u2i_ws, l0_u2i_as, cw0s_u2i, 64, 4, 64};
  ca.j[1] = {l0_u2i_wd, l0_u2i_ad, cw0d_u2i, 64, 4, 64};
  ca.j[2] = {l0_i2u_ws, l0_i2u_as, cw0s_i2u, 64, 4, 64};
  ca.j[3] = {l0_i2u_wd, l0_i2u_ad, cw0d_i2u, 64, 4, 64};
  ca.j[4] = {l1_u2i_ws, l1_u2i_as, cw1s_u2i, 256, 1, 32};
  ca.j[5] = {l1_u2i_wd, l1_u2i_ad, cw1d_u2i, 256, 1, 32};
  ca.j[6] = {l1_i2u_ws, l1_i2u_as, cw1s_i2u, 256, 1, 32};
  ca.j[7] = {l1_i2u_wd, l1_i2u_ad, cw1d_i2u, 256, 1, 32};
  collapse_kernel<<<8, 256, 0, stream>>>(ca);

  // ---- layer 0: src-side feature GEMMs (hd never materialized) ----
  gemm_kernel<64,false><<<dim3(GM,4), 256, 0, stream>>>(hu, l0_u2i_ws, nullptr, hs0_u2i, NN, 64, 256);
  gemm_kernel<64,false><<<dim3(GM,4), 256, 0, stream>>>(hi, l0_i2u_ws, nullptr, hs0_i2u, NN, 64, 256);

  // ---- layer 0: attention logits ----
  matvec_kernel<64,4><<<dim3(NN/4,4), 256, 0, stream>>>(
      MvJob{hu, cw0s_u2i, als0_u2i}, MvJob{hi, cw0d_u2i, ald0_u2i},
      MvJob{hi, cw0s_i2u, als0_i2u}, MvJob{hu, cw0d_i2u, ald0_i2u});

  // ---- layer 0: softmax-aggregate (+bias +ELU fused) ----
  agg0_kernel<<<dim3(NN/4,2), 256, 0, stream>>>(
      AggJob{offs_u2i, ssrc_u2i, hs0_u2i, als0_u2i, ald0_u2i, l0_u2i_b, hi1},
      AggJob{offs_i2u, ssrc_i2u, hs0_i2u, als0_i2u, ald0_i2u, l0_i2u_b, hu1});

  // ---- layer 1: src-side feature GEMMs ----
  gemm_kernel<32,false><<<dim3(GM,1), 256, 0, stream>>>(hu1, l1_u2i_ws, nullptr, hs1_u2i, NN, 256, 32);
  gemm_kernel<32,false><<<dim3(GM,1), 256, 0, stream>>>(hi1, l1_i2u_ws, nullptr, hs1_i2u, NN, 256, 32);

  // ---- layer 1: attention logits ----
  matvec_kernel<256,1><<<dim3(NN/4,4), 256, 0, stream>>>(
      MvJob{hu1, cw1s_u2i, als1_u2i}, MvJob{hi1, cw1d_u2i, ald1_u2i},
      MvJob{hi1, cw1s_i2u, als1_i2u}, MvJob{hu1, cw1d_i2u, ald1_i2u});

  // ---- layer 1: softmax-aggregate (+bias), writing final outputs ----
  float* hu2 = (float*)d_out;                  // first tuple element (dst = users, i2u)
  float* hi2 = (float*)d_out + (size_t)NN*32;  // second tuple element (dst = items, u2i)
  agg1_kernel<<<dim3(NN/4,2), 256, 0, stream>>>(
      AggJob{offs_u2i, ssrc_u2i, hs1_u2i, als1_u2i, ald1_u2i, l1_u2i_b, hi2},
      AggJob{offs_i2u, ssrc_i2u, hs1_i2u, als1_i2u, ald1_i2u, l1_i2u_b, hu2});
}

// Round 2
// 823.620 us; speedup vs baseline: 1.1507x; 1.1507x over previous
//
#include <hip/hip_runtime.h>
#include <cstdint>
#include <cstddef>

#define NN 50000
#define NE 800000
#define NEG_FLT_MAX (-3.402823466e38f)

__device__ __forceinline__ float lrelu_f(float x){ return x >= 0.f ? x : 0.2f*x; }
__device__ __forceinline__ float elu_f(float x){ return x > 0.f ? x : __expf(x) - 1.f; }

// bf16 helpers (RNE), stored as ushort
__device__ __forceinline__ unsigned short f2bf(float f){
  unsigned int u = __float_as_uint(f);
  u += 0x7FFFu + ((u >> 16) & 1u);
  return (unsigned short)(u >> 16);
}
__device__ __forceinline__ float bf2f(unsigned int us){
  return __uint_as_float(us << 16);
}
__device__ __forceinline__ float4 bf4_load(const unsigned short* p){
  uint2 q = *(const uint2*)p;
  return make_float4(bf2f(q.x & 0xffffu), bf2f(q.x >> 16),
                     bf2f(q.y & 0xffffu), bf2f(q.y >> 16));
}

// ---------------- counting sort (per edge type, by dst) ----------------
__global__ void hist_kernel(const int* __restrict__ e0, const int* __restrict__ e1,
                            int* __restrict__ c0, int* __restrict__ c1){
  int i = blockIdx.x*256 + threadIdx.x;
  const int* e = blockIdx.y ? e1 : e0;
  int* c = blockIdx.y ? c1 : c0;
  if (i < NE) atomicAdd(&c[e[NE + i]], 1);
}

__global__ __launch_bounds__(1024) void scan_kernel(int* d0, int* cu0, int* d1, int* cu1){
  int* data = blockIdx.x ? d1 : d0;
  int* cur  = blockIdx.x ? cu1 : cu0;
  __shared__ int sh[1024];
  const int t = threadIdx.x;
  int carry = 0;
  for (int base = 0; base < NN; base += 1024){
    int i = base + t;
    int v = (i < NN) ? data[i] : 0;
    sh[t] = v; __syncthreads();
    for (int off = 1; off < 1024; off <<= 1){
      int x = (t >= off) ? sh[t-off] : 0;
      __syncthreads();
      sh[t] += x;
      __syncthreads();
    }
    int incl = sh[t];
    int tot  = sh[1023];
    __syncthreads();
    int excl = carry + incl - v;
    if (i < NN){ data[i] = excl; cur[i] = excl; }
    carry += tot;
  }
  if (t == 0) data[NN] = carry;
}

__global__ void scatter_kernel(const int* __restrict__ e0, const int* __restrict__ e1,
                               int* __restrict__ cu0, int* __restrict__ cu1,
                               int* __restrict__ s0, int* __restrict__ s1){
  int i = blockIdx.x*256 + threadIdx.x;
  const int* e = blockIdx.y ? e1 : e0;
  int* cu = blockIdx.y ? cu1 : cu0;
  int* ss = blockIdx.y ? s1 : s0;
  if (i < NE){
    int d = e[NE + i];
    int p = atomicAdd(&cu[d], 1);
    ss[p] = e[i];
  }
}

// ---------------- tiled fp32 GEMM: C = act(A[M,K] @ W[K,N] (+bias)) ----------------
// TILE_M=64, TILE_K=64, TILE_N=TN (64 or 32). 256 threads; thread computes TN/16 rows x 4 cols.
// BF16OUT: store output as bf16 (ushort), used for edge-gather feature tables.
template<int TN, bool ELU, bool BF16OUT>
__global__ __launch_bounds__(256) void gemm_kernel(
    const float* __restrict__ A, const float* __restrict__ W,
    const float* __restrict__ bias, float* __restrict__ C,
    int M, int K, int N)
{
  constexpr int CG  = TN/4;    // column groups (float4 each)
  constexpr int RPT = TN/16;   // rows per thread
  __shared__ float As[64][68]; // +4 pad
  __shared__ float Ws[64][TN];
  const int t  = threadIdx.x;
  const int tx = t % CG;
  const int ty = t / CG;
  const int m0 = blockIdx.x * 64;
  const int n0 = blockIdx.y * TN;
  float acc[RPT][4];
  #pragma unroll
  for (int i=0;i<RPT;i++){ acc[i][0]=0.f; acc[i][1]=0.f; acc[i][2]=0.f; acc[i][3]=0.f; }

  for (int kt = 0; kt < K; kt += 64){
    #pragma unroll
    for (int i=0;i<4;i++){
      int li = t + i*256;
      int r = li >> 4, cv = li & 15;
      float4 v = make_float4(0.f,0.f,0.f,0.f);
      int m = m0 + r;
      if (m < M) v = *(const float4*)(A + (size_t)m*K + kt + cv*4);
      *(float4*)&As[r][cv*4] = v;
    }
    #pragma unroll
    for (int i=0;i<TN/16;i++){
      int li = t + i*256;
      int r = li / CG, cv = li % CG;
      *(float4*)&Ws[r][cv*4] = *(const float4*)(W + (size_t)(kt + r)*N + n0 + cv*4);
    }
    __syncthreads();
    #pragma unroll 16
    for (int k=0;k<64;k++){
      float4 wv = *(const float4*)&Ws[k][tx*4];
      #pragma unroll
      for (int i=0;i<RPT;i++){
        float a = As[ty*RPT + i][k];
        acc[i][0] += a*wv.x; acc[i][1] += a*wv.y;
        acc[i][2] += a*wv.z; acc[i][3] += a*wv.w;
      }
    }
    __syncthreads();
  }
  #pragma unroll
  for (int i=0;i<RPT;i++){
    int m = m0 + ty*RPT + i;
    if (m < M){
      float4 o = make_float4(acc[i][0],acc[i][1],acc[i][2],acc[i][3]);
      if (bias){
        float4 b = *(const float4*)(bias + n0 + tx*4);
        o.x+=b.x; o.y+=b.y; o.z+=b.z; o.w+=b.w;
      }
      if (ELU){ o.x=elu_f(o.x); o.y=elu_f(o.y); o.z=elu_f(o.z); o.w=elu_f(o.w); }
      if (BF16OUT){
        unsigned short* Cb = (unsigned short*)C;
        uint2 p;
        p.x = (unsigned)f2bf(o.x) | ((unsigned)f2bf(o.y) << 16);
        p.y = (unsigned)f2bf(o.z) | ((unsigned)f2bf(o.w) << 16);
        *(uint2*)(Cb + (size_t)m*N + n0 + tx*4) = p;
      } else {
        *(float4*)(C + (size_t)m*N + n0 + tx*4) = o;
      }
    }
  }
}

// ---------------- collapse attention vectors: cw[h,k] = sum_c W[k,h*C+c]*a[h,c] ----------------
struct CollapseJob { const float* W; const float* a; float* out; int K,H,C; };
struct CollapseArgs { CollapseJob j[8]; };
__global__ void collapse_kernel(CollapseArgs args){
  CollapseJob jb = args.j[blockIdx.x];
  int t = threadIdx.x;
  if (t < jb.K * jb.H){
    int k = t / jb.H, h = t % jb.H;
    const float* wr = jb.W + (size_t)k * (jb.H*jb.C) + h*jb.C;
    const float* ar = jb.a + h*jb.C;
    float s = 0.f;
    for (int c=0;c<jb.C;c++) s += wr[c]*ar[c];
    jb.out[h*jb.K + k] = s;   // layout [H,K]
  }
}

// ---------------- fused dual matvec: for one X, compute alA[n,h]=X[n,:].cwA[h,:]
// and alB[n,h]=X[n,:].cwB[h,:] in one pass (X streamed once). wave per node.
struct Mv2Job { const float* X; const float* cwA; const float* cwB; float* outA; float* outB; };
template<int K, int H>
__global__ __launch_bounds__(256) void matvec2_kernel(Mv2Job j0, Mv2Job j1){
  Mv2Job jb = blockIdx.y ? j1 : j0;
  __shared__ float cwa[K*H];
  __shared__ float cwb[K*H];
  for (int i=threadIdx.x; i<K*H; i+=256){ cwa[i] = jb.cwA[i]; cwb[i] = jb.cwB[i]; }
  __syncthreads();
  const int wid = threadIdx.x>>6, lane = threadIdx.x&63;
  const int node = blockIdx.x*4 + wid;
  if (node >= NN) return;
  float pa[H], pb[H];
  #pragma unroll
  for (int h=0;h<H;h++){ pa[h]=0.f; pb[h]=0.f; }
  #pragma unroll
  for (int kk=0; kk<K/64; kk++){
    float x = jb.X[(size_t)node*K + kk*64 + lane];
    #pragma unroll
    for (int h=0;h<H;h++){
      pa[h] += x*cwa[h*K + kk*64 + lane];
      pb[h] += x*cwb[h*K + kk*64 + lane];
    }
  }
  #pragma unroll
  for (int off=32; off>0; off>>=1){
    #pragma unroll
    for (int h=0;h<H;h++){
      pa[h] += __shfl_xor(pa[h], off, 64);
      pb[h] += __shfl_xor(pb[h], off, 64);
    }
  }
  if (lane==0){
    #pragma unroll
    for (int h=0;h<H;h++){
      jb.outA[(size_t)node*H + h] = pa[h];
      jb.outB[(size_t)node*H + h] = pb[h];
    }
  }
}

// ---------------- GAT aggregation ----------------
struct AggJob {
  const int* offs; const int* ssrc;
  const unsigned short* hs;          // bf16 feature table
  const float* als; const float* ald;
  const float* bias; float* out;
};

// layer 0: H=4, C=64 (256 ch bf16). One wave per dst; lane l owns channels 4l..4l+3 (head l>>4).
__global__ __launch_bounds__(256) void agg0_kernel(AggJob ja, AggJob jbb){
  const AggJob jb = blockIdx.y ? jbb : ja;
  const int wid = threadIdx.x>>6, lane = threadIdx.x&63;
  const int dst = blockIdx.x*4 + wid;
  if (dst >= NN) return;
  const int b0 = jb.offs[dst], b1 = jb.offs[dst+1];
  const float4 ad = *(const float4*)(jb.ald + (size_t)dst*4);
  float mx0=NEG_FLT_MAX, mx1=NEG_FLT_MAX, mx2=NEG_FLT_MAX, mx3=NEG_FLT_MAX;
  for (int e=b0+lane; e<b1; e+=64){
    int s = jb.ssrc[e];
    float4 as = *(const float4*)(jb.als + (size_t)s*4);
    mx0 = fmaxf(mx0, lrelu_f(as.x+ad.x));
    mx1 = fmaxf(mx1, lrelu_f(as.y+ad.y));
    mx2 = fmaxf(mx2, lrelu_f(as.z+ad.z));
    mx3 = fmaxf(mx3, lrelu_f(as.w+ad.w));
  }
  #pragma unroll
  for (int off=32; off>0; off>>=1){
    mx0 = fmaxf(mx0, __shfl_xor(mx0, off, 64));
    mx1 = fmaxf(mx1, __shfl_xor(mx1, off, 64));
    mx2 = fmaxf(mx2, __shfl_xor(mx2, off, 64));
    mx3 = fmaxf(mx3, __shfl_xor(mx3, off, 64));
  }
  const int h = lane >> 4;
  const float mh  = (h<2) ? (h==0?mx0:mx1) : (h==2?mx2:mx3);
  const float adh = (h<2) ? (h==0?ad.x:ad.y) : (h==2?ad.z:ad.w);
  float4 acc = make_float4(0.f,0.f,0.f,0.f);
  float den = 0.f;
  int e = b0;
  for (; e+2<=b1; e+=2){
    int s0 = jb.ssrc[e], s1 = jb.ssrc[e+1];
    float4 v0 = bf4_load(jb.hs + (size_t)s0*256 + lane*4);
    float4 v1 = bf4_load(jb.hs + (size_t)s1*256 + lane*4);
    float w0 = __expf(lrelu_f(jb.als[(size_t)s0*4 + h] + adh) - mh);
    float w1 = __expf(lrelu_f(jb.als[(size_t)s1*4 + h] + adh) - mh);
    acc.x += w0*v0.x + w1*v1.x;
    acc.y += w0*v0.y + w1*v1.y;
    acc.z += w0*v0.z + w1*v1.z;
    acc.w += w0*v0.w + w1*v1.w;
    den += w0 + w1;
  }
  if (e < b1){
    int s = jb.ssrc[e];
    float4 v = bf4_load(jb.hs + (size_t)s*256 + lane*4);
    float w = __expf(lrelu_f(jb.als[(size_t)s*4 + h] + adh) - mh);
    acc.x += w*v.x; acc.y += w*v.y; acc.z += w*v.z; acc.w += w*v.w;
    den += w;
  }
  const float inv = 1.f/(den + 1e-16f);
  float4 b = *(const float4*)(jb.bias + lane*4);
  float4 o;
  o.x = elu_f(acc.x*inv + b.x);
  o.y = elu_f(acc.y*inv + b.y);
  o.z = elu_f(acc.z*inv + b.z);
  o.w = elu_f(acc.w*inv + b.w);
  *(float4*)(jb.out + (size_t)dst*256 + lane*4) = o;
}

// layer 1: H=1, C=32 bf16. One wave per dst; 8 edge slots x (8 lanes * 4ch) per edge row.
__global__ __launch_bounds__(256) void agg1_kernel(AggJob ja, AggJob jbb){
  const AggJob jb = blockIdx.y ? jbb : ja;
  const int wid = threadIdx.x>>6, lane = threadIdx.x&63;
  const int dst = blockIdx.x*4 + wid;
  if (dst >= NN) return;
  const int b0 = jb.offs[dst], b1 = jb.offs[dst+1];
  const float ad = jb.ald[dst];
  float mx = NEG_FLT_MAX;
  for (int e=b0+lane; e<b1; e+=64)
    mx = fmaxf(mx, lrelu_f(jb.als[jb.ssrc[e]] + ad));
  #pragma unroll
  for (int off=32; off>0; off>>=1) mx = fmaxf(mx, __shfl_xor(mx, off, 64));
  const int slot = lane>>3, c4 = (lane&7)*4;
  float4 acc = make_float4(0.f,0.f,0.f,0.f);
  float den = 0.f;
  int e = b0 + slot;
  for (; e+8 < b1; e += 16){
    int s0 = jb.ssrc[e], s1 = jb.ssrc[e+8];
    float4 v0 = bf4_load(jb.hs + (size_t)s0*32 + c4);
    float4 v1 = bf4_load(jb.hs + (size_t)s1*32 + c4);
    float w0 = __expf(lrelu_f(jb.als[s0] + ad) - mx);
    float w1 = __expf(lrelu_f(jb.als[s1] + ad) - mx);
    acc.x += w0*v0.x + w1*v1.x;
    acc.y += w0*v0.y + w1*v1.y;
    acc.z += w0*v0.z + w1*v1.z;
    acc.w += w0*v0.w + w1*v1.w;
    den += w0 + w1;
  }
  if (e < b1){
    int s = jb.ssrc[e];
    float4 v = bf4_load(jb.hs + (size_t)s*32 + c4);
    float w = __expf(lrelu_f(jb.als[s] + ad) - mx);
    acc.x += w*v.x; acc.y += w*v.y; acc.z += w*v.z; acc.w += w*v.w;
    den += w;
  }
  #pragma unroll
  for (int off=32; off>=8; off>>=1){
    acc.x += __shfl_xor(acc.x, off, 64);
    acc.y += __shfl_xor(acc.y, off, 64);
    acc.z += __shfl_xor(acc.z, off, 64);
    acc.w += __shfl_xor(acc.w, off, 64);
    den   += __shfl_xor(den,   off, 64);
  }
  if (lane < 8){
    const float inv = 1.f/(den + 1e-16f);
    float4 b = *(const float4*)(jb.bias + c4);
    float4 o = make_float4(acc.x*inv+b.x, acc.y*inv+b.y, acc.z*inv+b.z, acc.w*inv+b.w);
    *(float4*)(jb.out + (size_t)dst*32 + c4) = o;
  }
}

// ---------------- host glue ----------------
extern "C" void kernel_launch(void* const* d_in, const int* in_sizes, int n_in,
                              void* d_out, int out_size, void* d_ws, size_t ws_size,
                              hipStream_t stream)
{
  (void)in_sizes; (void)n_in; (void)out_size; (void)ws_size;
  const float* x_user   = (const float*)d_in[0];
  const float* x_item   = (const float*)d_in[1];
  const int*   e_u2i    = (const int*)  d_in[2];
  const int*   e_i2u    = (const int*)  d_in[3];
  const float* p_user_w = (const float*)d_in[4];
  const float* p_user_b = (const float*)d_in[5];
  const float* p_item_w = (const float*)d_in[6];
  const float* p_item_b = (const float*)d_in[7];
  const float* l0_u2i_ws=(const float*)d_in[8];
  const float* l0_u2i_wd=(const float*)d_in[9];
  const float* l0_u2i_as=(const float*)d_in[10];
  const float* l0_u2i_ad=(const float*)d_in[11];
  const float* l0_u2i_b =(const float*)d_in[12];
  const float* l0_i2u_ws=(const float*)d_in[13];
  const float* l0_i2u_wd=(const float*)d_in[14];
  const float* l0_i2u_as=(const float*)d_in[15];
  const float* l0_i2u_ad=(const float*)d_in[16];
  const float* l0_i2u_b =(const float*)d_in[17];
  const float* l1_u2i_ws=(const float*)d_in[18];
  const float* l1_u2i_wd=(const float*)d_in[19];
  const float* l1_u2i_as=(const float*)d_in[20];
  const float* l1_u2i_ad=(const float*)d_in[21];
  const float* l1_u2i_b =(const float*)d_in[22];
  const float* l1_i2u_ws=(const float*)d_in[23];
  const float* l1_i2u_wd=(const float*)d_in[24];
  const float* l1_i2u_as=(const float*)d_in[25];
  const float* l1_i2u_ad=(const float*)d_in[26];
  const float* l1_i2u_b =(const float*)d_in[27];

  char* base = (char*)d_ws;
  size_t off = 0;
  auto alloc = [&](size_t bytes)->void*{
    void* p = base + off;
    off += (bytes + 255) & ~(size_t)255;
    return p;
  };
  int* offs_u2i = (int*)alloc((size_t)2*(NN+1)*sizeof(int));
  int* offs_i2u = offs_u2i + (NN+1);
  int* cur_u2i  = (int*)alloc((size_t)NN*sizeof(int));
  int* cur_i2u  = (int*)alloc((size_t)NN*sizeof(int));
  int* ssrc_u2i = (int*)alloc((size_t)NE*sizeof(int));
  int* ssrc_i2u = (int*)alloc((size_t)NE*sizeof(int));
  float* hu       = (float*)alloc((size_t)NN*64*sizeof(float));
  float* hi       = (float*)alloc((size_t)NN*64*sizeof(float));
  unsigned short* hs0_u2i = (unsigned short*)alloc((size_t)NN*256*sizeof(unsigned short));
  unsigned short* hs0_i2u = (unsigned short*)alloc((size_t)NN*256*sizeof(unsigned short));
  float* hu1      = (float*)alloc((size_t)NN*256*sizeof(float));
  float* hi1      = (float*)alloc((size_t)NN*256*sizeof(float));
  unsigned short* hs1_u2i = (unsigned short*)alloc((size_t)NN*32*sizeof(unsigned short));
  unsigned short* hs1_i2u = (unsigned short*)alloc((size_t)NN*32*sizeof(unsigned short));
  float* als0_u2i = (float*)alloc((size_t)NN*4*sizeof(float));
  float* ald0_u2i = (float*)alloc((size_t)NN*4*sizeof(float));
  float* als0_i2u = (float*)alloc((size_t)NN*4*sizeof(float));
  float* ald0_i2u = (float*)alloc((size_t)NN*4*sizeof(float));
  float* als1_u2i = (float*)alloc((size_t)NN*sizeof(float));
  float* ald1_u2i = (float*)alloc((size_t)NN*sizeof(float));
  float* als1_i2u = (float*)alloc((size_t)NN*sizeof(float));
  float* ald1_i2u = (float*)alloc((size_t)NN*sizeof(float));
  float* cw0s_u2i = (float*)alloc(256*sizeof(float));
  float* cw0d_u2i = (float*)alloc(256*sizeof(float));
  float* cw0s_i2u = (float*)alloc(256*sizeof(float));
  float* cw0d_i2u = (float*)alloc(256*sizeof(float));
  float* cw1s_u2i = (float*)alloc(256*sizeof(float));
  float* cw1d_u2i = (float*)alloc(256*sizeof(float));
  float* cw1s_i2u = (float*)alloc(256*sizeof(float));
  float* cw1d_i2u = (float*)alloc(256*sizeof(float));

  const int GEB = (NE + 255)/256;
  const int GM  = (NN + 63)/64;

  // ---- counting sort of both edge lists by dst ----
  hipMemsetAsync(offs_u2i, 0, (size_t)2*(NN+1)*sizeof(int), stream);
  hist_kernel   <<<dim3(GEB,2), 256, 0, stream>>>(e_u2i, e_i2u, offs_u2i, offs_i2u);
  scan_kernel   <<<2, 1024, 0, stream>>>(offs_u2i, cur_u2i, offs_i2u, cur_i2u);
  scatter_kernel<<<dim3(GEB,2), 256, 0, stream>>>(e_u2i, e_i2u, cur_u2i, cur_i2u, ssrc_u2i, ssrc_i2u);

  // ---- input projections (+bias +ELU) ----
  gemm_kernel<64,true,false><<<dim3(GM,1), 256, 0, stream>>>(x_user, p_user_w, p_user_b, hu, NN, 128, 64);
  gemm_kernel<64,true,false><<<dim3(GM,1), 256, 0, stream>>>(x_item, p_item_w, p_item_b, hi, NN, 128, 64);

  // ---- collapse attention vectors through the linear weights ----
  CollapseArgs ca;
  ca.j[0] = {l0_u2i_ws, l0_u2i_as, cw0s_u2i, 64, 4, 64};
  ca.j[1] = {l0_u2i_wd, l0_u2i_ad, cw0d_u2i, 64, 4, 64};
  ca.j[2] = {l0_i2u_ws, l0_i2u_as, cw0s_i2u, 64, 4, 64};
  ca.j[3] = {l0_i2u_wd, l0_i2u_ad, cw0d_i2u, 64, 4, 64};
  ca.j[4] = {l1_u2i_ws, l1_u2i_as, cw1s_u2i, 256, 1, 32};
  ca.j[5] = {l1_u2i_wd, l1_u2i_ad, cw1d_u2i, 256, 1, 32};
  ca.j[6] = {l1_i2u_ws, l1_i2u_as, cw1s_i2u, 256, 1, 32};
  ca.j[7] = {l1_i2u_wd, l1_i2u_ad, cw1d_i2u, 256, 1, 32};
  collapse_kernel<<<8, 256, 0, stream>>>(ca);

  // ---- layer 0: src-side feature GEMMs -> bf16 gather tables ----
  gemm_kernel<64,false,true><<<dim3(GM,4), 256, 0, stream>>>(hu, l0_u2i_ws, nullptr, (float*)hs0_u2i, NN, 64, 256);
  gemm_kernel<64,false,true><<<dim3(GM,4), 256, 0, stream>>>(hi, l0_i2u_ws, nullptr, (float*)hs0_i2u, NN, 64, 256);

  // ---- layer 0: attention logits (fused: each X streamed once for both uses) ----
  matvec2_kernel<64,4><<<dim3(NN/4,2), 256, 0, stream>>>(
      Mv2Job{hu, cw0s_u2i, cw0d_i2u, als0_u2i, ald0_i2u},
      Mv2Job{hi, cw0s_i2u, cw0d_u2i, als0_i2u, ald0_u2i});

  // ---- layer 0: softmax-aggregate (+bias +ELU fused) ----
  agg0_kernel<<<dim3(NN/4,2), 256, 0, stream>>>(
      AggJob{offs_u2i, ssrc_u2i, hs0_u2i, als0_u2i, ald0_u2i, l0_u2i_b, hi1},
      AggJob{offs_i2u, ssrc_i2u, hs0_i2u, als0_i2u, ald0_i2u, l0_i2u_b, hu1});

  // ---- layer 1: src-side feature GEMMs -> bf16 gather tables ----
  gemm_kernel<32,false,true><<<dim3(GM,1), 256, 0, stream>>>(hu1, l1_u2i_ws, nullptr, (float*)hs1_u2i, NN, 256, 32);
  gemm_kernel<32,false,true><<<dim3(GM,1), 256, 0, stream>>>(hi1, l1_i2u_ws, nullptr, (float*)hs1_i2u, NN, 256, 32);

  // ---- layer 1: attention logits (fused) ----
  matvec2_kernel<256,1><<<dim3(NN/4,2), 256, 0, stream>>>(
      Mv2Job{hu1, cw1s_u2i, cw1d_i2u, als1_u2i, ald1_i2u},
      Mv2Job{hi1, cw1s_i2u, cw1d_u2i, als1_i2u, ald1_u2i});

  // ---- layer 1: softmax-aggregate (+bias), writing final outputs ----
  float* hu2 = (float*)d_out;                  // first tuple element (dst = users, i2u)
  float* hi2 = (float*)d_out + (size_t)NN*32;  // second tuple element (dst = items, u2i)
  agg1_kernel<<<dim3(NN/4,2), 256, 0, stream>>>(
      AggJob{offs_u2i, ssrc_u2i, hs1_u2i, als1_u2i, ald1_u2i, l1_u2i_b, hi2},
      AggJob{offs_i2u, ssrc_i2u, hs1_i2u, als1_i2u, ald1_i2u, l1_i2u_b, hu2});
}

// Round 3
// 738.032 us; speedup vs baseline: 1.2841x; 1.1160x over previous
//
#include <hip/hip_runtime.h>
#include <cstdint>
#include <cstddef>

#define NN 50000
#define NE 800000
#define NEG_FLT_MAX (-3.402823466e38f)

typedef __attribute__((ext_vector_type(8))) short short8;
typedef __attribute__((ext_vector_type(4))) float floatx4;

__device__ __forceinline__ float lrelu_f(float x){ return x >= 0.f ? x : 0.2f*x; }
__device__ __forceinline__ float elu_f(float x){ return x > 0.f ? x : __expf(x) - 1.f; }

// bf16 helpers (RNE), stored as ushort
__device__ __forceinline__ unsigned short f2bf(float f){
  unsigned int u = __float_as_uint(f);
  u += 0x7FFFu + ((u >> 16) & 1u);
  return (unsigned short)(u >> 16);
}
__device__ __forceinline__ float bf2f(unsigned int us){
  return __uint_as_float(us << 16);
}
__device__ __forceinline__ float4 bf4_load(const unsigned short* p){
  uint2 q = *(const uint2*)p;
  return make_float4(bf2f(q.x & 0xffffu), bf2f(q.x >> 16),
                     bf2f(q.y & 0xffffu), bf2f(q.y >> 16));
}
__device__ __forceinline__ void split_bf(float a, unsigned short& h, unsigned short& l){
  h = f2bf(a);
  l = f2bf(a - bf2f(h));
}

// ---------------- counting sort (per edge type, by dst) ----------------
__global__ void hist_kernel(const int* __restrict__ e0, const int* __restrict__ e1,
                            int* __restrict__ c0, int* __restrict__ c1){
  int i = blockIdx.x*256 + threadIdx.x;
  const int* e = blockIdx.y ? e1 : e0;
  int* c = blockIdx.y ? c1 : c0;
  if (i < NE) atomicAdd(&c[e[NE + i]], 1);
}

// wave-shuffle scan: 3 barriers per 1024-chunk instead of 20
__global__ __launch_bounds__(1024) void scan_kernel(int* d0, int* cu0, int* d1, int* cu1){
  int* data = blockIdx.x ? d1 : d0;
  int* cur  = blockIdx.x ? cu1 : cu0;
  __shared__ int shw[16];
  __shared__ int shbase[17];
  const int t = threadIdx.x, wv = t>>6, l = t&63;
  int carry = 0;
  for (int base = 0; base < NN; base += 1024){
    int i = base + t;
    int v = (i < NN) ? data[i] : 0;
    int sum = v;
    #pragma unroll
    for (int off=1; off<64; off<<=1){
      int x = __shfl_up(sum, off, 64);
      if (l >= off) sum += x;
    }
    if (l == 63) shw[wv] = sum;
    __syncthreads();
    if (t < 16){
      int wsum = shw[t];
      int s2 = wsum;
      #pragma unroll
      for (int off=1; off<16; off<<=1){
        int x = __shfl_up(s2, off, 64);
        if (t >= off) s2 += x;
      }
      shbase[t] = s2 - wsum;
      if (t == 15) shbase[16] = s2;
    }
    __syncthreads();
    int excl = carry + shbase[wv] + (sum - v);
    if (i < NN){ data[i] = excl; cur[i] = excl; }
    carry += shbase[16];
    __syncthreads();
  }
  if (t == 0) data[NN] = carry;
}

// scatter: also writes dst_sorted and layer-0 edge alpha (sorted order)
__global__ void scatter_kernel(const int* __restrict__ e0, const int* __restrict__ e1,
                               int* __restrict__ cu0, int* __restrict__ cu1,
                               int* __restrict__ s0, int* __restrict__ s1,
                               int* __restrict__ dd0, int* __restrict__ dd1,
                               const float* __restrict__ alsA, const float* __restrict__ aldA,
                               const float* __restrict__ alsB, const float* __restrict__ aldB,
                               float* __restrict__ alp0, float* __restrict__ alp1){
  int i = blockIdx.x*256 + threadIdx.x;
  const int* e = blockIdx.y ? e1 : e0;
  int* cu = blockIdx.y ? cu1 : cu0;
  int* ss = blockIdx.y ? s1 : s0;
  int* dd = blockIdx.y ? dd1 : dd0;
  const float* als = blockIdx.y ? alsB : alsA;
  const float* ald = blockIdx.y ? aldB : aldA;
  float* alp = blockIdx.y ? alp1 : alp0;
  if (i < NE){
    int s = e[i];
    int d = e[NE + i];
    int p = atomicAdd(&cu[d], 1);
    ss[p] = s; dd[p] = d;
    float4 a = *(const float4*)(als + (size_t)s*4);
    float4 b = *(const float4*)(ald + (size_t)d*4);
    float4 o = make_float4(lrelu_f(a.x+b.x), lrelu_f(a.y+b.y),
                           lrelu_f(a.z+b.z), lrelu_f(a.w+b.w));
    *(float4*)(alp + (size_t)p*4) = o;
  }
}

// layer-1 edge alpha (sorted order, coalesced except small als gather)
__global__ void edge_alpha1_kernel(const int* __restrict__ ss0, const int* __restrict__ dd0,
                                   const int* __restrict__ ss1, const int* __restrict__ dd1,
                                   const float* __restrict__ alsA, const float* __restrict__ aldA,
                                   const float* __restrict__ alsB, const float* __restrict__ aldB,
                                   float* __restrict__ o0, float* __restrict__ o1){
  int i = blockIdx.x*256 + threadIdx.x;
  const int* ss = blockIdx.y ? ss1 : ss0;
  const int* dd = blockIdx.y ? dd1 : dd0;
  const float* als = blockIdx.y ? alsB : alsA;
  const float* ald = blockIdx.y ? aldB : aldA;
  float* o = blockIdx.y ? o1 : o0;
  if (i < NE) o[i] = lrelu_f(als[ss[i]] + ald[dd[i]]);
}

// ---------------- MFMA split-bf16 GEMM: C = act(A[M,K] @ W[K,N] (+bias)) ----------------
// tile 64(M) x NT*16(N), BK=64. fp32 inputs are split to (hi,lo) bf16 in LDS;
// 3-product accumulation AhBh+AhBl+AlBh gives near-fp32 accuracy at MFMA rate.
template<int NT, bool ELU, bool BF16OUT>
__global__ __launch_bounds__(256) void mgemm_kernel(
    const float* __restrict__ A, const float* __restrict__ W,
    const float* __restrict__ bias, void* __restrict__ Cv,
    int M, int K, int N)
{
  constexpr int TN = NT*16;
  __shared__ __align__(16) unsigned short Ah[64*72];
  __shared__ __align__(16) unsigned short Al[64*72];
  __shared__ __align__(16) unsigned short Bh[TN*72];
  __shared__ __align__(16) unsigned short Bl[TN*72];
  const int t = threadIdx.x;
  const int m0 = blockIdx.x*64;
  const int n0 = blockIdx.y*TN;
  const int wv = t>>6, l = t&63;
  const int lr = l&15, lq = l>>4;
  floatx4 acc[NT];
  #pragma unroll
  for (int i=0;i<NT;i++) acc[i] = (floatx4){0.f,0.f,0.f,0.f};

  for (int kt=0; kt<K; kt+=64){
    // stage A (64x64 fp32 -> split bf16), row-major [64][72]
    #pragma unroll
    for (int i=0;i<4;i++){
      int li = t + i*256;
      int r = li >> 4, c4 = (li & 15)*4;
      float4 v = make_float4(0.f,0.f,0.f,0.f);
      if (m0 + r < M) v = *(const float4*)(A + (size_t)(m0+r)*K + kt + c4);
      unsigned short h0,h1,h2,h3,g0,g1,g2,g3;
      split_bf(v.x,h0,g0); split_bf(v.y,h1,g1);
      split_bf(v.z,h2,g2); split_bf(v.w,h3,g3);
      uint2 ph = { (unsigned)h0 | ((unsigned)h1<<16), (unsigned)h2 | ((unsigned)h3<<16) };
      uint2 pl = { (unsigned)g0 | ((unsigned)g1<<16), (unsigned)g2 | ((unsigned)g3<<16) };
      *(uint2*)&Ah[r*72 + c4] = ph;
      *(uint2*)&Al[r*72 + c4] = pl;
    }
    // stage W transposed: Bt[n][k], [TN][72]
    #pragma unroll
    for (int i=0;i<NT;i++){
      int li = t + i*256;
      int k  = li / (TN/4);
      int n4 = (li % (TN/4))*4;
      float4 v = *(const float4*)(W + (size_t)(kt+k)*N + n0 + n4);
      unsigned short h, g;
      split_bf(v.x,h,g); Bh[(n4+0)*72+k]=h; Bl[(n4+0)*72+k]=g;
      split_bf(v.y,h,g); Bh[(n4+1)*72+k]=h; Bl[(n4+1)*72+k]=g;
      split_bf(v.z,h,g); Bh[(n4+2)*72+k]=h; Bl[(n4+2)*72+k]=g;
      split_bf(v.w,h,g); Bh[(n4+3)*72+k]=h; Bl[(n4+3)*72+k]=g;
    }
    __syncthreads();
    #pragma unroll
    for (int ks=0; ks<2; ks++){
      const int koff = ks*32 + lq*8;
      short8 a_h = *(const short8*)&Ah[(wv*16+lr)*72 + koff];
      short8 a_l = *(const short8*)&Al[(wv*16+lr)*72 + koff];
      #pragma unroll
      for (int nt=0; nt<NT; nt++){
        short8 b_h = *(const short8*)&Bh[(nt*16+lr)*72 + koff];
        short8 b_l = *(const short8*)&Bl[(nt*16+lr)*72 + koff];
        acc[nt] = __builtin_amdgcn_mfma_f32_16x16x32_bf16(a_h, b_h, acc[nt], 0,0,0);
        acc[nt] = __builtin_amdgcn_mfma_f32_16x16x32_bf16(a_h, b_l, acc[nt], 0,0,0);
        acc[nt] = __builtin_amdgcn_mfma_f32_16x16x32_bf16(a_l, b_h, acc[nt], 0,0,0);
      }
    }
    __syncthreads();
  }
  // epilogue: C/D layout col=lane&15, row=quad*4+reg
  #pragma unroll
  for (int nt=0; nt<NT; nt++){
    int n = n0 + nt*16 + lr;
    float bv = bias ? bias[n] : 0.f;
    #pragma unroll
    for (int r=0;r<4;r++){
      int m = m0 + wv*16 + lq*4 + r;
      if (m < M){
        float o = acc[nt][r] + bv;
        if (ELU) o = elu_f(o);
        if (BF16OUT) ((unsigned short*)Cv)[(size_t)m*N + n] = f2bf(o);
        else         ((float*)Cv)[(size_t)m*N + n] = o;
      }
    }
  }
}

// ---------------- collapse attention vectors: cw[h,k] = sum_c W[k,h*C+c]*a[h,c] ----------------
struct CollapseJob { const float* W; const float* a; float* out; int K,H,C; };
struct CollapseArgs { CollapseJob j[8]; };
__global__ void collapse_kernel(CollapseArgs args){
  CollapseJob jb = args.j[blockIdx.x];
  int t = threadIdx.x;
  if (t < jb.K * jb.H){
    int k = t / jb.H, h = t % jb.H;
    const float* wr = jb.W + (size_t)k * (jb.H*jb.C) + h*jb.C;
    const float* ar = jb.a + h*jb.C;
    float s = 0.f;
    for (int c=0;c<jb.C;c++) s += wr[c]*ar[c];
    jb.out[h*jb.K + k] = s;   // layout [H,K]
  }
}

// ---------------- fused dual matvec ----------------
struct Mv2Job { const float* X; const float* cwA; const float* cwB; float* outA; float* outB; };
template<int K, int H>
__global__ __launch_bounds__(256) void matvec2_kernel(Mv2Job j0, Mv2Job j1){
  Mv2Job jb = blockIdx.y ? j1 : j0;
  __shared__ float cwa[K*H];
  __shared__ float cwb[K*H];
  for (int i=threadIdx.x; i<K*H; i+=256){ cwa[i] = jb.cwA[i]; cwb[i] = jb.cwB[i]; }
  __syncthreads();
  const int wid = threadIdx.x>>6, lane = threadIdx.x&63;
  const int node = blockIdx.x*4 + wid;
  if (node >= NN) return;
  float pa[H], pb[H];
  #pragma unroll
  for (int h=0;h<H;h++){ pa[h]=0.f; pb[h]=0.f; }
  #pragma unroll
  for (int kk=0; kk<K/64; kk++){
    float x = jb.X[(size_t)node*K + kk*64 + lane];
    #pragma unroll
    for (int h=0;h<H;h++){
      pa[h] += x*cwa[h*K + kk*64 + lane];
      pb[h] += x*cwb[h*K + kk*64 + lane];
    }
  }
  #pragma unroll
  for (int off=32; off>0; off>>=1){
    #pragma unroll
    for (int h=0;h<H;h++){
      pa[h] += __shfl_xor(pa[h], off, 64);
      pb[h] += __shfl_xor(pb[h], off, 64);
    }
  }
  if (lane==0){
    #pragma unroll
    for (int h=0;h<H;h++){
      jb.outA[(size_t)node*H + h] = pa[h];
      jb.outB[(size_t)node*H + h] = pb[h];
    }
  }
}

// ---------------- GAT aggregation ----------------
struct Agg0Job {
  const int* offs; const int* ssrc;
  const unsigned short* hs;   // bf16 [NN,256]
  const float* alpha;         // sorted [E,4]
  const float* bias; float* out;
};

// layer 0: H=4, C=64. wave per dst; lane l owns channels 4l..4l+3 (head l>>4).
__global__ __launch_bounds__(256) void agg0_kernel(Agg0Job ja, Agg0Job jbb){
  const Agg0Job jb = blockIdx.y ? jbb : ja;
  const int wid = threadIdx.x>>6, lane = threadIdx.x&63;
  const int dst = blockIdx.x*4 + wid;
  if (dst >= NN) return;
  const int b0 = jb.offs[dst], b1 = jb.offs[dst+1];
  float mx0=NEG_FLT_MAX, mx1=NEG_FLT_MAX, mx2=NEG_FLT_MAX, mx3=NEG_FLT_MAX;
  for (int e=b0+lane; e<b1; e+=64){
    float4 a = *(const float4*)(jb.alpha + (size_t)e*4);
    mx0 = fmaxf(mx0, a.x); mx1 = fmaxf(mx1, a.y);
    mx2 = fmaxf(mx2, a.z); mx3 = fmaxf(mx3, a.w);
  }
  #pragma unroll
  for (int off=32; off>0; off>>=1){
    mx0 = fmaxf(mx0, __shfl_xor(mx0, off, 64));
    mx1 = fmaxf(mx1, __shfl_xor(mx1, off, 64));
    mx2 = fmaxf(mx2, __shfl_xor(mx2, off, 64));
    mx3 = fmaxf(mx3, __shfl_xor(mx3, off, 64));
  }
  const int h = lane >> 4;
  const float mh = (h<2) ? (h==0?mx0:mx1) : (h==2?mx2:mx3);
  const unsigned short* hsp = jb.hs + (size_t)lane*4;
  float4 acc = make_float4(0.f,0.f,0.f,0.f);
  float den = 0.f;
  int e = b0;
  for (; e+4<=b1; e+=4){
    int s0 = jb.ssrc[e],   s1 = jb.ssrc[e+1];
    int s2 = jb.ssrc[e+2], s3 = jb.ssrc[e+3];
    float a0 = jb.alpha[(size_t)e*4 + h];
    float a1 = jb.alpha[(size_t)(e+1)*4 + h];
    float a2 = jb.alpha[(size_t)(e+2)*4 + h];
    float a3 = jb.alpha[(size_t)(e+3)*4 + h];
    float4 v0 = bf4_load(hsp + (size_t)s0*256);
    float4 v1 = bf4_load(hsp + (size_t)s1*256);
    float4 v2 = bf4_load(hsp + (size_t)s2*256);
    float4 v3 = bf4_load(hsp + (size_t)s3*256);
    float w0 = __expf(a0 - mh), w1 = __expf(a1 - mh);
    float w2 = __expf(a2 - mh), w3 = __expf(a3 - mh);
    acc.x += w0*v0.x + w1*v1.x + w2*v2.x + w3*v3.x;
    acc.y += w0*v0.y + w1*v1.y + w2*v2.y + w3*v3.y;
    acc.z += w0*v0.z + w1*v1.z + w2*v2.z + w3*v3.z;
    acc.w += w0*v0.w + w1*v1.w + w2*v2.w + w3*v3.w;
    den += (w0+w1) + (w2+w3);
  }
  for (; e<b1; ++e){
    int s = jb.ssrc[e];
    float a = jb.alpha[(size_t)e*4 + h];
    float4 v = bf4_load(hsp + (size_t)s*256);
    float w = __expf(a - mh);
    acc.x += w*v.x; acc.y += w*v.y; acc.z += w*v.z; acc.w += w*v.w;
    den += w;
  }
  const float inv = 1.f/(den + 1e-16f);
  float4 b = *(const float4*)(jb.bias + lane*4);
  float4 o;
  o.x = elu_f(acc.x*inv + b.x);
  o.y = elu_f(acc.y*inv + b.y);
  o.z = elu_f(acc.z*inv + b.z);
  o.w = elu_f(acc.w*inv + b.w);
  *(float4*)(jb.out + (size_t)dst*256 + lane*4) = o;
}

struct Agg1Job {
  const int* offs; const int* ssrc;
  const unsigned short* hs;   // bf16 [NN,32]
  const float* alpha;         // sorted [E]
  const float* bias; float* out;
};

// layer 1: H=1, C=32. wave per dst; 8 edge slots x (8 lanes * 4ch).
__global__ __launch_bounds__(256) void agg1_kernel(Agg1Job ja, Agg1Job jbb){
  const Agg1Job jb = blockIdx.y ? jbb : ja;
  const int wid = threadIdx.x>>6, lane = threadIdx.x&63;
  const int dst = blockIdx.x*4 + wid;
  if (dst >= NN) return;
  const int b0 = jb.offs[dst], b1 = jb.offs[dst+1];
  float mx = NEG_FLT_MAX;
  for (int e=b0+lane; e<b1; e+=64) mx = fmaxf(mx, jb.alpha[e]);
  #pragma unroll
  for (int off=32; off>0; off>>=1) mx = fmaxf(mx, __shfl_xor(mx, off, 64));
  const int slot = lane>>3, c4 = (lane&7)*4;
  float4 acc = make_float4(0.f,0.f,0.f,0.f);
  float den = 0.f;
  int e = b0 + slot;
  for (; e+8 < b1; e += 16){
    int s0 = jb.ssrc[e], s1 = jb.ssrc[e+8];
    float w0 = __expf(jb.alpha[e] - mx);
    float w1 = __expf(jb.alpha[e+8] - mx);
    float4 v0 = bf4_load(jb.hs + (size_t)s0*32 + c4);
    float4 v1 = bf4_load(jb.hs + (size_t)s1*32 + c4);
    acc.x += w0*v0.x + w1*v1.x;
    acc.y += w0*v0.y + w1*v1.y;
    acc.z += w0*v0.z + w1*v1.z;
    acc.w += w0*v0.w + w1*v1.w;
    den += w0 + w1;
  }
  if (e < b1){
    int s = jb.ssrc[e];
    float w = __expf(jb.alpha[e] - mx);
    float4 v = bf4_load(jb.hs + (size_t)s*32 + c4);
    acc.x += w*v.x; acc.y += w*v.y; acc.z += w*v.z; acc.w += w*v.w;
    den += w;
  }
  #pragma unroll
  for (int off=32; off>=8; off>>=1){
    acc.x += __shfl_xor(acc.x, off, 64);
    acc.y += __shfl_xor(acc.y, off, 64);
    acc.z += __shfl_xor(acc.z, off, 64);
    acc.w += __shfl_xor(acc.w, off, 64);
    den   += __shfl_xor(den,   off, 64);
  }
  if (lane < 8){
    const float inv = 1.f/(den + 1e-16f);
    float4 b = *(const float4*)(jb.bias + c4);
    float4 o = make_float4(acc.x*inv+b.x, acc.y*inv+b.y, acc.z*inv+b.z, acc.w*inv+b.w);
    *(float4*)(jb.out + (size_t)dst*32 + c4) = o;
  }
}

// ---------------- host glue ----------------
extern "C" void kernel_launch(void* const* d_in, const int* in_sizes, int n_in,
                              void* d_out, int out_size, void* d_ws, size_t ws_size,
                              hipStream_t stream)
{
  (void)in_sizes; (void)n_in; (void)out_size; (void)ws_size;
  const float* x_user   = (const float*)d_in[0];
  const float* x_item   = (const float*)d_in[1];
  const int*   e_u2i    = (const int*)  d_in[2];
  const int*   e_i2u    = (const int*)  d_in[3];
  const float* p_user_w = (const float*)d_in[4];
  const float* p_user_b = (const float*)d_in[5];
  const float* p_item_w = (const float*)d_in[6];
  const float* p_item_b = (const float*)d_in[7];
  const float* l0_u2i_ws=(const float*)d_in[8];
  const float* l0_u2i_wd=(const float*)d_in[9];
  const float* l0_u2i_as=(const float*)d_in[10];
  const float* l0_u2i_ad=(const float*)d_in[11];
  const float* l0_u2i_b =(const float*)d_in[12];
  const float* l0_i2u_ws=(const float*)d_in[13];
  const float* l0_i2u_wd=(const float*)d_in[14];
  const float* l0_i2u_as=(const float*)d_in[15];
  const float* l0_i2u_ad=(const float*)d_in[16];
  const float* l0_i2u_b =(const float*)d_in[17];
  const float* l1_u2i_ws=(const float*)d_in[18];
  const float* l1_u2i_wd=(const float*)d_in[19];
  const float* l1_u2i_as=(const float*)d_in[20];
  const float* l1_u2i_ad=(const float*)d_in[21];
  const float* l1_u2i_b =(const float*)d_in[22];
  const float* l1_i2u_ws=(const float*)d_in[23];
  const float* l1_i2u_wd=(const float*)d_in[24];
  const float* l1_i2u_as=(const float*)d_in[25];
  const float* l1_i2u_ad=(const float*)d_in[26];
  const float* l1_i2u_b =(const float*)d_in[27];

  char* base = (char*)d_ws;
  size_t off = 0;
  auto alloc = [&](size_t bytes)->void*{
    void* p = base + off;
    off += (bytes + 255) & ~(size_t)255;
    return p;
  };
  int* offs_u2i = (int*)alloc((size_t)2*(NN+1)*sizeof(int));
  int* offs_i2u = offs_u2i + (NN+1);
  int* cur_u2i  = (int*)alloc((size_t)NN*sizeof(int));
  int* cur_i2u  = (int*)alloc((size_t)NN*sizeof(int));
  int* ssrc_u2i = (int*)alloc((size_t)NE*sizeof(int));
  int* ssrc_i2u = (int*)alloc((size_t)NE*sizeof(int));
  int* dsts_u2i = (int*)alloc((size_t)NE*sizeof(int));
  int* dsts_i2u = (int*)alloc((size_t)NE*sizeof(int));
  float* alpha0_u2i = (float*)alloc((size_t)NE*4*sizeof(float));
  float* alpha0_i2u = (float*)alloc((size_t)NE*4*sizeof(float));
  float* alpha1_u2i = (float*)alloc((size_t)NE*sizeof(float));
  float* alpha1_i2u = (float*)alloc((size_t)NE*sizeof(float));
  float* hu       = (float*)alloc((size_t)NN*64*sizeof(float));
  float* hi       = (float*)alloc((size_t)NN*64*sizeof(float));
  unsigned short* hs0_u2i = (unsigned short*)alloc((size_t)NN*256*sizeof(unsigned short));
  unsigned short* hs0_i2u = (unsigned short*)alloc((size_t)NN*256*sizeof(unsigned short));
  float* hu1      = (float*)alloc((size_t)NN*256*sizeof(float));
  float* hi1      = (float*)alloc((size_t)NN*256*sizeof(float));
  unsigned short* hs1_u2i = (unsigned short*)alloc((size_t)NN*32*sizeof(unsigned short));
  unsigned short* hs1_i2u = (unsigned short*)alloc((size_t)NN*32*sizeof(unsigned short));
  float* als0_u2i = (float*)alloc((size_t)NN*4*sizeof(float));
  float* ald0_u2i = (float*)alloc((size_t)NN*4*sizeof(float));
  float* als0_i2u = (float*)alloc((size_t)NN*4*sizeof(float));
  float* ald0_i2u = (float*)alloc((size_t)NN*4*sizeof(float));
  float* als1_u2i = (float*)alloc((size_t)NN*sizeof(float));
  float* ald1_u2i = (float*)alloc((size_t)NN*sizeof(float));
  float* als1_i2u = (float*)alloc((size_t)NN*sizeof(float));
  float* ald1_i2u = (float*)alloc((size_t)NN*sizeof(float));
  float* cw0s_u2i = (float*)alloc(256*sizeof(float));
  float* cw0d_u2i = (float*)alloc(256*sizeof(float));
  float* cw0s_i2u = (float*)alloc(256*sizeof(float));
  float* cw0d_i2u = (float*)alloc(256*sizeof(float));
  float* cw1s_u2i = (float*)alloc(256*sizeof(float));
  float* cw1d_u2i = (float*)alloc(256*sizeof(float));
  float* cw1s_i2u = (float*)alloc(256*sizeof(float));
  float* cw1d_i2u = (float*)alloc(256*sizeof(float));

  const int GEB = (NE + 255)/256;
  const int GM  = (NN + 63)/64;

  // ---- histogram + scan ----
  hipMemsetAsync(offs_u2i, 0, (size_t)2*(NN+1)*sizeof(int), stream);
  hist_kernel<<<dim3(GEB,2), 256, 0, stream>>>(e_u2i, e_i2u, offs_u2i, offs_i2u);
  scan_kernel<<<2, 1024, 0, stream>>>(offs_u2i, cur_u2i, offs_i2u, cur_i2u);

  // ---- input projections (+bias +ELU), MFMA ----
  mgemm_kernel<4,true,false><<<dim3(GM,1), 256, 0, stream>>>(x_user, p_user_w, p_user_b, hu, NN, 128, 64);
  mgemm_kernel<4,true,false><<<dim3(GM,1), 256, 0, stream>>>(x_item, p_item_w, p_item_b, hi, NN, 128, 64);

  // ---- collapse attention vectors ----
  CollapseArgs ca;
  ca.j[0] = {l0_u2i_ws, l0_u2i_as, cw0s_u2i, 64, 4, 64};
  ca.j[1] = {l0_u2i_wd, l0_u2i_ad, cw0d_u2i, 64, 4, 64};
  ca.j[2] = {l0_i2u_ws, l0_i2u_as, cw0s_i2u, 64, 4, 64};
  ca.j[3] = {l0_i2u_wd, l0_i2u_ad, cw0d_i2u, 64, 4, 64};
  ca.j[4] = {l1_u2i_ws, l1_u2i_as, cw1s_u2i, 256, 1, 32};
  ca.j[5] = {l1_u2i_wd, l1_u2i_ad, cw1d_u2i, 256, 1, 32};
  ca.j[6] = {l1_i2u_ws, l1_i2u_as, cw1s_i2u, 256, 1, 32};
  ca.j[7] = {l1_i2u_wd, l1_i2u_ad, cw1d_i2u, 256, 1, 32};
  collapse_kernel<<<8, 256, 0, stream>>>(ca);

  // ---- layer 0 logits ----
  matvec2_kernel<64,4><<<dim3(NN/4,2), 256, 0, stream>>>(
      Mv2Job{hu, cw0s_u2i, cw0d_i2u, als0_u2i, ald0_i2u},
      Mv2Job{hi, cw0s_i2u, cw0d_u2i, als0_i2u, ald0_u2i});

  // ---- scatter (sorted src/dst + sorted layer-0 alpha) ----
  scatter_kernel<<<dim3(GEB,2), 256, 0, stream>>>(
      e_u2i, e_i2u, cur_u2i, cur_i2u,
      ssrc_u2i, ssrc_i2u, dsts_u2i, dsts_i2u,
      als0_u2i, ald0_u2i, als0_i2u, ald0_i2u,
      alpha0_u2i, alpha0_i2u);

  // ---- layer 0: src-side feature GEMMs -> bf16 gather tables ----
  mgemm_kernel<4,false,true><<<dim3(GM,4), 256, 0, stream>>>(hu, l0_u2i_ws, nullptr, hs0_u2i, NN, 64, 256);
  mgemm_kernel<4,false,true><<<dim3(GM,4), 256, 0, stream>>>(hi, l0_i2u_ws, nullptr, hs0_i2u, NN, 64, 256);

  // ---- layer 0: softmax-aggregate (+bias +ELU) ----
  agg0_kernel<<<dim3(NN/4,2), 256, 0, stream>>>(
      Agg0Job{offs_u2i, ssrc_u2i, hs0_u2i, alpha0_u2i, l0_u2i_b, hi1},
      Agg0Job{offs_i2u, ssrc_i2u, hs0_i2u, alpha0_i2u, l0_i2u_b, hu1});

  // ---- layer 1: src-side feature GEMMs -> bf16 gather tables ----
  mgemm_kernel<2,false,true><<<dim3(GM,1), 256, 0, stream>>>(hu1, l1_u2i_ws, nullptr, hs1_u2i, NN, 256, 32);
  mgemm_kernel<2,false,true><<<dim3(GM,1), 256, 0, stream>>>(hi1, l1_i2u_ws, nullptr, hs1_i2u, NN, 256, 32);

  // ---- layer 1 logits ----
  matvec2_kernel<256,1><<<dim3(NN/4,2), 256, 0, stream>>>(
      Mv2Job{hu1, cw1s_u2i, cw1d_i2u, als1_u2i, ald1_i2u},
      Mv2Job{hi1, cw1s_i2u, cw1d_u2i, als1_i2u, ald1_u2i});

  // ---- layer 1: sorted edge alpha ----
  edge_alpha1_kernel<<<dim3(GEB,2), 256, 0, stream>>>(
      ssrc_u2i, dsts_u2i, ssrc_i2u, dsts_i2u,
      als1_u2i, ald1_u2i, als1_i2u, ald1_i2u,
      alpha1_u2i, alpha1_i2u);

  // ---- layer 1: softmax-aggregate (+bias), final outputs ----
  float* hu2 = (float*)d_out;                  // first tuple element (users, i2u dst)
  float* hi2 = (float*)d_out + (size_t)NN*32;  // second tuple element (items, u2i dst)
  agg1_kernel<<<dim3(NN/4,2), 256, 0, stream>>>(
      Agg1Job{offs_u2i, ssrc_u2i, hs1_u2i, alpha1_u2i, l1_u2i_b, hi2},
      Agg1Job{offs_i2u, ssrc_i2u, hs1_i2u, alpha1_i2u, l1_i2u_b, hu2});
}